// Round 1
// baseline (222.716 us; speedup 1.0000x reference)
//
#include <hip/hip_runtime.h>

#define NPOS 21824          // 16384+4096+1024+256+64 positions per image
#define NC   3320           // 1000+1000+1000+256+64 candidates per image
#define MINS 0.05f

struct Ptrs { const float* cls[5]; const float* reg[5]; const float* ctr[5]; };

__device__ __forceinline__ float sigf(float x){ return 1.0f/(1.0f+expf(-x)); }

// ---------------- Kernel A: score / class / box, 4 lanes per position -------
__global__ __launch_bounds__(256) void k_score(Ptrs P, float* scoreAll, int* clsAll,
                                               float4* boxAll)
{
    int img  = blockIdx.y;
    int blk  = blockIdx.x;           // [0,341)
    int tid  = threadIdx.x;
    int posb = tid >> 2;             // position within block [0,64)
    int l    = tid & 3;              // lane within 4-lane group
    int p    = blk*64 + posb;
    int lvl, base, lw, stride;
    if (blk < 256)      { lvl=0; base=0;     lw=7; stride=8;   }
    else if (blk < 320) { lvl=1; base=16384; lw=6; stride=16;  }
    else if (blk < 336) { lvl=2; base=20480; lw=5; stride=32;  }
    else if (blk < 340) { lvl=3; base=21504; lw=4; stride=64;  }
    else                { lvl=4; base=21760; lw=3; stride=128; }
    int pl = p - base;
    int h = pl >> lw, w = pl & ((1<<lw)-1);
    long long lidx = (long long)img*(1<<(2*lw)) + pl;

    const float4* c4 = (const float4*)(P.cls[lvl] + lidx*80);
    float mx = -3.4e38f; int mi = 0;
#pragma unroll
    for (int j = 0; j < 5; ++j) {
        int k = j*4 + l;
        float4 v = c4[k];
        int cb = k*4;
        if (v.x > mx){mx=v.x; mi=cb;}
        if (v.y > mx){mx=v.y; mi=cb+1;}
        if (v.z > mx){mx=v.z; mi=cb+2;}
        if (v.w > mx){mx=v.w; mi=cb+3;}
    }
#pragma unroll
    for (int d = 1; d < 4; d <<= 1) {
        float omx = __shfl_xor(mx, d);
        int   omi = __shfl_xor(mi, d);
        if (omx > mx || (omx == mx && omi < mi)) { mx = omx; mi = omi; }
    }
    if (l == 0) {
        float ct = P.ctr[lvl][lidx];
        float sc = sqrtf(sigf(mx)*sigf(ct));   // sigmoid(max)==max(sigmoid)
        float4 rg = ((const float4*)P.reg[lvl])[lidx];
        float x = (w + 0.5f)*(float)stride;
        float y = (h + 0.5f)*(float)stride;
        int ix1 = (int)(x - expf(rg.x));
        int iy1 = (int)(y - expf(rg.y));
        int ix2 = (int)(x + expf(rg.z));
        int iy2 = (int)(y + expf(rg.w));
        ix1 = max(ix1,0); iy1 = max(iy1,0);
        ix2 = min(ix2,1023); iy2 = min(iy2,1023);
        int o = img*NPOS + p;
        scoreAll[o] = sc;
        clsAll[o]   = mi;
        boxAll[o]   = make_float4((float)ix1,(float)iy1,(float)ix2,(float)iy2);
    }
}

// ---- exact K-th-largest u32, 3-pass radix (19/8/0), wave suffix scan -------
// Monotone bins: scores are positive floats < 2.0 -> bits>>19 < 2048.
__device__ void radix_sel(const unsigned int* vals, int N, int K,
                          int* hist, int* wsum, unsigned int* shPref, int* shK,
                          int tid)
{
    if (tid == 0) { *shPref = 0; *shK = K; }
    __syncthreads();
    const int shv[3] = {19, 8, 0};
    const int nbv[3] = {2048, 2048, 256};
    for (int pass = 0; pass < 3; ++pass) {
        int sh = shv[pass], nb = nbv[pass];
        unsigned int pref = *shPref;
        int K2 = *shK;
        for (int i = tid; i < nb; i += 256) hist[i] = 0;
        __syncthreads();
#pragma unroll 4
        for (int i = tid; i < N; i += 256) {
            unsigned int b = vals[i];
            bool match = (pass == 0) ||
                         (pass == 1 ? ((b >> 19) == (pref >> 19))
                                    : ((b >> 8)  == (pref >> 8)));
            if (match) atomicAdd(&hist[(b >> sh) & (nb - 1)], 1);
        }
        __syncthreads();
        int g = nb >> 8, lo = tid * g, ls = 0;
        for (int q = 0; q < g; ++q) ls += hist[lo + q];
        int lane = tid & 63, wv = tid >> 6;
        int v = ls;
#pragma unroll
        for (int off = 1; off < 64; off <<= 1) {
            int o = __shfl_down(v, off);
            if (lane + off < 64) v += o;
        }
        if (lane == 0) wsum[wv] = v;     // wave total (lane0 suffix = whole wave)
        __syncthreads();
        int add = 0;
        for (int q = wv + 1; q < 4; ++q) add += wsum[q];
        int mine = v + add;              // suffix sum threads [tid..255]
        int above = mine - ls;           // suffix sum threads (tid..255]
        if (above < K2 && mine >= K2) {  // exactly one thread crosses
            int cum = above;
            for (int b = lo + g - 1; b >= lo; --b) {
                cum += hist[b];
                if (cum >= K2) {
                    *shPref = pref | ((unsigned int)b << sh);
                    *shK = K2 - (cum - hist[b]);
                    break;
                }
            }
        }
        __syncthreads();
    }
}

// --- Kernel B: per-(img,lvl) exact top-1000 -> cKeyG (32 blocks parallel) ---
// key = (score_bits<<16) | (65535-p): desc key == desc score, ties lower p.
__global__ __launch_bounds__(256) void k_thresh(const float* scoreAll,
                                                unsigned long long* cKeyG)
{
    __shared__ int hist[2048];
    __shared__ int wsum[4];
    __shared__ unsigned int shPref;
    __shared__ int shK, tick, eqn;
    __shared__ int eq[1024];
    int il = blockIdx.x, tid = threadIdx.x;

    if (il >= 24) {                      // blocks 24..31: levels 3+4 copier
        int img = il - 24;
        const unsigned int* gs = (const unsigned int*)scoreAll + (long long)img*NPOS;
        unsigned long long* gk = cKeyG + (long long)img*NC;
        for (int i = tid; i < 320; i += 256) {
            int p = 21504 + i;
            gk[3000 + i] = ((unsigned long long)gs[p] << 16) | (unsigned)(65535 - p);
        }
        return;
    }
    int img = il / 3, lvl = il % 3;
    const int baseA[3] = {0, 16384, 20480};
    const int NlA[3]   = {16384, 4096, 1024};
    const int cbA[3]   = {0, 1000, 2000};
    int base = baseA[lvl], Nl = NlA[lvl];
    const unsigned int* gs = (const unsigned int*)scoreAll + (long long)img*NPOS + base;
    unsigned long long* gk = cKeyG + (long long)img*NC + cbA[lvl];

    radix_sel(gs, Nl, 1000, hist, wsum, &shPref, &shK, tid);
    if (tid == 0) { tick = 0; eqn = 0; }
    __syncthreads();
    unsigned int kth = shPref;
    int need = shK;                      // #ties to keep (>=1)
#pragma unroll 4
    for (int i = tid; i < Nl; i += 256) {
        unsigned int b = gs[i];
        if (b > kth) {
            int t = atomicAdd(&tick, 1);
            int p = base + i;
            gk[t] = ((unsigned long long)b << 16) | (unsigned)(65535 - p);
        } else if (b == kth) {
            int t = atomicAdd(&eqn, 1);
            if (t < 1024) eq[t] = i;
        }
    }
    __syncthreads();
    int m = eqn, nG = tick;              // nG == 1000-need
    if (m <= 1024) {                     // keep the `need` LOWEST tie indices
        for (int q = tid; q < m; q += 256) {
            int iq = eq[q], r = 0;
            for (int j = 0; j < m; ++j) r += (eq[j] < iq);
            if (r < need) {
                int p = base + iq;
                gk[nG + r] = ((unsigned long long)kth << 16) | (unsigned)(65535 - p);
            }
        }
    } else if (tid == 0) {               // unreachable-in-practice fallback
        int cnt = 0;
        for (int i = 0; i < Nl && cnt < need; ++i)
            if (gs[i] == kth) {
                int p = base + i;
                gk[nG + cnt] = ((unsigned long long)kth << 16) | (unsigned)(65535 - p);
                ++cnt;
            }
    }
}

// ------ Kernel C: top-256 select + rank + matrix-NMS (8 blocks) -------------
// Greedy NMS == sequential scan over rank order with a 256-bit suppression
// mask: candidate i accepted iff bit i clear; on accept, OR in row i of the
// precomputed (parallel-built) IoU>thr matrix. Identical decisions to the
// serial greedy walk, but per-candidate serial cost drops from ~300cy
// (IoU chain + __ballot) to ~5cy (bit test), and only accepts pay an LDS
// row load (~130cy).
__global__ __launch_bounds__(256) void k_nms2(const unsigned long long* cKeyG,
                                              const float4* boxAll, const int* clsAll,
                                              float* out)
{
    __shared__ unsigned long long cand[NC];
    __shared__ unsigned int cbits[NC];
    __shared__ int hist[2048];
    __shared__ int wsum[4];
    __shared__ unsigned int shPref;
    __shared__ int shK, tick, eqn;
    __shared__ int eq[256];
    __shared__ unsigned long long sel[256];
    __shared__ unsigned long long sorted[256];
    __shared__ float4 sBox[256];
    __shared__ float  sCls[256];
    __shared__ __align__(16) unsigned long long sRow[256][4];
    __shared__ int accIdx[100];
    __shared__ int shNaM, shNaT;

    int img = blockIdx.x, tid = threadIdx.x;
    const float4* gBox = boxAll + (long long)img*NPOS;
    const int*    gCls = clsAll + (long long)img*NPOS;
    const unsigned long long* gKey = cKeyG + (long long)img*NC;

    float* outS = out + img*100;
    float* outC = out + 800 + img*100;
    float* outB = out + 1600 + img*400;

    for (int i = tid; i < NC; i += 256) {
        unsigned long long k = gKey[i];
        cand[i]  = k;
        cbits[i] = (unsigned int)(k >> 16);
    }
    __syncthreads();

    radix_sel(cbits, NC, 256, hist, wsum, &shPref, &shK, tid);
    if (tid == 0) { tick = 0; eqn = 0; }
    __syncthreads();
    unsigned int kth2 = shPref;
    int need2 = shK;
    for (int i = tid; i < NC; i += 256) {
        unsigned int b = cbits[i];
        if (b > kth2)       { int t = atomicAdd(&tick, 1); sel[t] = cand[i]; }
        else if (b == kth2) { int t = atomicAdd(&eqn, 1); if (t < 256) eq[t] = i; }
    }
    __syncthreads();
    int m2 = eqn, nG2 = tick;            // nG2 == 256-need2
    if (m2 <= 256) {                     // keep `need2` LARGEST keys among ties
        for (int q = tid; q < m2; q += 256) {
            unsigned long long kq = cand[eq[q]];
            int r = 0;
            for (int j = 0; j < m2; ++j) r += (cand[eq[j]] > kq);
            if (r < need2) sel[nG2 + r] = kq;
        }
    } else if (tid == 0) {               // unreachable-in-practice fallback
        unsigned long long last = ~0ULL;
        for (int c = 0; c < need2; ++c) {
            unsigned long long best = 0;
            for (int i = 0; i < NC; ++i) {
                unsigned long long k = cand[i];
                if ((unsigned int)(k >> 16) == kth2 && k < last && k > best) best = k;
            }
            sel[nG2 + c] = best; last = best;
        }
    }
    __syncthreads();

    // rank 256 unique keys by counting (1 key/thread, broadcast LDS reads)
    {
        unsigned long long k = sel[tid];
        int r = 0;
        for (int j = 0; j < 256; ++j) r += (sel[j] > k);
        sorted[r] = k;
    }
    __syncthreads();
    {
        int p = 65535 - (int)(sorted[tid] & 0xFFFF);
        sBox[tid] = gBox[p];
        sCls[tid] = (float)gCls[p];
    }

    // nValid = # leading candidates with score > MINS (sorted desc, so prefix).
    // __syncthreads_count doubles as the barrier covering sBox/sCls writes.
    float myScore = __uint_as_float((unsigned int)(sorted[tid] >> 16));
    int nValid = __syncthreads_count(myScore > MINS ? 1 : 0);

    // ---- suppression matrix: thread i builds row i (bits j>i, IoU>0.6) ----
    // Float arithmetic order matches the old serial walk exactly:
    // den = area(candidate j) + area(accepted i) - inter + 1e-12.
    {
        float4 bi = sBox[tid];
        float  ai = (bi.z-bi.x)*(bi.w-bi.y);
        unsigned long long m0=0, m1=0, m2_=0, m3=0;
        int w0 = tid >> 6;               // wave id (guards are wave-uniform)
#define FCOS_MBLK(MV, JB)                                                  \
        if (w0 <= (JB)) {                                                  \
            _Pragma("unroll 8")                                            \
            for (int jj = 0; jj < 64; ++jj) {                              \
                int j = (JB)*64 + jj;                                      \
                float4 bj = sBox[j];                                       \
                float aj = (bj.z-bj.x)*(bj.w-bj.y);                        \
                float iw = fmaxf(fminf(bj.z,bi.z)-fmaxf(bj.x,bi.x),0.f);   \
                float ih = fmaxf(fminf(bj.w,bi.w)-fmaxf(bj.y,bi.y),0.f);   \
                float in_ = iw*ih;                                         \
                bool s = (j > tid) && (in_/(aj+ai-in_+1e-12f) > 0.6f);     \
                MV |= ((unsigned long long)s) << jj;                       \
            }                                                              \
        }
        FCOS_MBLK(m0,0) FCOS_MBLK(m1,1) FCOS_MBLK(m2_,2) FCOS_MBLK(m3,3)
#undef FCOS_MBLK
        sRow[tid][0]=m0; sRow[tid][1]=m1; sRow[tid][2]=m2_; sRow[tid][3]=m3;
    }
    __syncthreads();

    // ---- serial bitmask walk (thread 0): ~5cy/suppressed, ~130cy/accept ----
    if (tid == 0) {
        int na = 0;
        unsigned long long r0=0, r1=0, r2=0, r3=0;
#define FCOS_WBLK(RW, IB)                                                  \
        {                                                                  \
            int hi = nValid < ((IB)+1)*64 ? nValid : ((IB)+1)*64;          \
            for (int i = (IB)*64; i < hi && na < 100; ++i) {               \
                if ((RW >> (i - (IB)*64)) & 1ull) continue;                \
                accIdx[na++] = i;                                          \
                const ulonglong2* rp = (const ulonglong2*)sRow[i];         \
                ulonglong2 ra = rp[0], rb = rp[1];                         \
                r0 |= ra.x; r1 |= ra.y; r2 |= rb.x; r3 |= rb.y;            \
            }                                                              \
        }
        FCOS_WBLK(r0,0) FCOS_WBLK(r1,1) FCOS_WBLK(r2,2) FCOS_WBLK(r3,3)
#undef FCOS_WBLK
        shNaM = na; shNaT = na;
    }

    // ---- fallback: top-256 exhausted before 100 accepted (never on real data)
    if (tid < 64) {
        int lane = tid;
        int naM = shNaM;                 // lane-0 LDS write, same wave: visible
        if (naM < 100 && nValid == 256) {
            int na = naM;
            float4 aB0 = make_float4(0,0,0,0), aB1 = make_float4(0,0,0,0);
            float  aA0 = 0.f, aA1 = 0.f;
            if (lane < na)      { aB0 = sBox[accIdx[lane]];
                                  aA0 = (aB0.z-aB0.x)*(aB0.w-aB0.y); }
            if (lane + 64 < na) { aB1 = sBox[accIdx[lane+64]];
                                  aA1 = (aB1.z-aB1.x)*(aB1.w-aB1.y); }
            unsigned long long thr = sorted[255];
            for (int j = lane; j < NC; j += 64)
                if (cand[j] >= thr) cand[j] = 0ULL;    // already consumed
            __threadfence_block();
            while (na < 100) {
                unsigned long long bk = 0; int bidx = -1;
                for (int j = lane; j < NC; j += 64) {
                    unsigned long long v = cand[j];
                    if (v > bk) { bk = v; bidx = j; }
                }
#pragma unroll
                for (int off = 32; off > 0; off >>= 1) {
                    unsigned long long ov = __shfl_down(bk, off);
                    int oi = __shfl_down(bidx, off);
                    if (ov > bk) { bk = ov; bidx = oi; }
                }
                bk = __shfl(bk, 0); bidx = __shfl(bidx, 0);
                if (bk == 0ULL) break;
                float sc = __uint_as_float((unsigned int)(bk >> 16));
                if (!(sc > MINS)) break;
                int p = 65535 - (int)(bk & 0xFFFF);
                float4 bb2 = gBox[p];
                float ba = (bb2.z-bb2.x)*(bb2.w-bb2.y);
                bool sup = false;
                if (lane < na) {
                    float iw = fmaxf(fminf(bb2.z,aB0.z)-fmaxf(bb2.x,aB0.x),0.f);
                    float ih = fmaxf(fminf(bb2.w,aB0.w)-fmaxf(bb2.y,aB0.y),0.f);
                    float in_ = iw*ih;
                    sup = in_/(ba+aA0-in_+1e-12f) > 0.6f;
                }
                if (lane + 64 < na) {
                    float iw = fmaxf(fminf(bb2.z,aB1.z)-fmaxf(bb2.x,aB1.x),0.f);
                    float ih = fmaxf(fminf(bb2.w,aB1.w)-fmaxf(bb2.y,aB1.y),0.f);
                    float in_ = iw*ih;
                    sup = sup || (in_/(ba+aA1-in_+1e-12f) > 0.6f);
                }
                if (__ballot(sup) == 0ULL) {
                    if (lane == 0) {
                        outS[na] = sc;
                        outC[na] = (float)gCls[p];
                        outB[4*na+0]=bb2.x; outB[4*na+1]=bb2.y;
                        outB[4*na+2]=bb2.z; outB[4*na+3]=bb2.w;
                    }
                    if (lane == (na & 63)) {
                        if (na < 64) { aB0 = bb2; aA0 = ba; }
                        else         { aB1 = bb2; aA1 = ba; }
                    }
                    ++na;
                }
                if (lane == 0) cand[bidx] = 0ULL;
                __threadfence_block();
            }
            if (lane == 0) shNaT = na;
        }
    }
    __syncthreads();

    // ---- parallel epilogue: main accepts from LDS; -1 fill for the rest ----
    {
        int naM = shNaM, naT = shNaT;
        if (tid < 100) {
            if (tid < naM) {
                int r = accIdx[tid];
                unsigned long long k = sorted[r];
                float4 b = sBox[r];
                outS[tid] = __uint_as_float((unsigned int)(k >> 16));
                outC[tid] = sCls[r];
                outB[4*tid+0]=b.x; outB[4*tid+1]=b.y;
                outB[4*tid+2]=b.z; outB[4*tid+3]=b.w;
            } else if (tid >= naT) {     // (naM..naT) written by fallback
                outS[tid] = -1.f; outC[tid] = -1.f;
                outB[4*tid+0]=-1.f; outB[4*tid+1]=-1.f;
                outB[4*tid+2]=-1.f; outB[4*tid+3]=-1.f;
            }
        }
    }
}

extern "C" void kernel_launch(void* const* d_in, const int* in_sizes, int n_in,
                              void* d_out, int out_size, void* d_ws, size_t ws_size,
                              hipStream_t stream) {
    Ptrs P;
    bool interleaved = (in_sizes[1] == 8 * 128 * 128 * 4);
    for (int i = 0; i < 5; ++i) {
        if (interleaved) {
            P.cls[i] = (const float*)d_in[3*i];
            P.reg[i] = (const float*)d_in[3*i + 1];
            P.ctr[i] = (const float*)d_in[3*i + 2];
        } else {
            P.cls[i] = (const float*)d_in[i];
            P.reg[i] = (const float*)d_in[5 + i];
            P.ctr[i] = (const float*)d_in[10 + i];
        }
    }

    char* wbase = (char*)d_ws;
    size_t off = 0;
    auto alloc = [&](size_t bytes) -> void* {
        void* r = wbase + off;
        off += (bytes + 255) & ~(size_t)255;
        return r;
    };
    float*              scoreAll = (float*)alloc((size_t)8 * NPOS * 4);
    int*                clsAll   = (int*)alloc((size_t)8 * NPOS * 4);
    float4*             boxAll   = (float4*)alloc((size_t)8 * NPOS * 16);
    unsigned long long* cKeyG    = (unsigned long long*)alloc((size_t)8 * NC * 8);

    dim3 gA(341, 8);   // 341*64 = 21824 positions, level boundaries block-aligned
    k_score <<<gA, 256, 0, stream>>>(P, scoreAll, clsAll, boxAll);
    k_thresh<<<32, 256, 0, stream>>>(scoreAll, cKeyG);
    k_nms2  <<<8, 256, 0, stream>>>(cKeyG, boxAll, clsAll, (float*)d_out);
}

// Round 2
// 162.647 us; speedup vs baseline: 1.3693x; 1.3693x over previous
//
#include <hip/hip_runtime.h>

#define NPOS 21824          // 16384+4096+1024+256+64 positions per image
#define NCK  1088           // 256*3 + 256 + 64 candidates per image (top-256/level)
#define MINS 0.05f
#define BT   1024           // threads per block for k_thresh / k_nms2 (16 waves)
#define NW   (BT/64)

struct Ptrs { const float* cls[5]; const float* reg[5]; const float* ctr[5]; };

__device__ __forceinline__ float sigf(float x){ return 1.0f/(1.0f+expf(-x)); }

// ---------------- Kernel A: score / class / box, 4 lanes per position -------
__global__ __launch_bounds__(256) void k_score(Ptrs P, float* scoreAll, int* clsAll,
                                               float4* boxAll)
{
    int img  = blockIdx.y;
    int blk  = blockIdx.x;           // [0,341)
    int tid  = threadIdx.x;
    int posb = tid >> 2;             // position within block [0,64)
    int l    = tid & 3;              // lane within 4-lane group
    int p    = blk*64 + posb;
    int lvl, base, lw, stride;
    if (blk < 256)      { lvl=0; base=0;     lw=7; stride=8;   }
    else if (blk < 320) { lvl=1; base=16384; lw=6; stride=16;  }
    else if (blk < 336) { lvl=2; base=20480; lw=5; stride=32;  }
    else if (blk < 340) { lvl=3; base=21504; lw=4; stride=64;  }
    else                { lvl=4; base=21760; lw=3; stride=128; }
    int pl = p - base;
    int h = pl >> lw, w = pl & ((1<<lw)-1);
    long long lidx = (long long)img*(1<<(2*lw)) + pl;

    const float4* c4 = (const float4*)(P.cls[lvl] + lidx*80);
    float mx = -3.4e38f; int mi = 0;
#pragma unroll
    for (int j = 0; j < 5; ++j) {
        int k = j*4 + l;
        float4 v = c4[k];
        int cb = k*4;
        if (v.x > mx){mx=v.x; mi=cb;}
        if (v.y > mx){mx=v.y; mi=cb+1;}
        if (v.z > mx){mx=v.z; mi=cb+2;}
        if (v.w > mx){mx=v.w; mi=cb+3;}
    }
#pragma unroll
    for (int d = 1; d < 4; d <<= 1) {
        float omx = __shfl_xor(mx, d);
        int   omi = __shfl_xor(mi, d);
        if (omx > mx || (omx == mx && omi < mi)) { mx = omx; mi = omi; }
    }
    if (l == 0) {
        float ct = P.ctr[lvl][lidx];
        float sc = sqrtf(sigf(mx)*sigf(ct));   // sigmoid(max)==max(sigmoid)
        float4 rg = ((const float4*)P.reg[lvl])[lidx];
        float x = (w + 0.5f)*(float)stride;
        float y = (h + 0.5f)*(float)stride;
        int ix1 = (int)(x - expf(rg.x));
        int iy1 = (int)(y - expf(rg.y));
        int ix2 = (int)(x + expf(rg.z));
        int iy2 = (int)(y + expf(rg.w));
        ix1 = max(ix1,0); iy1 = max(iy1,0);
        ix2 = min(ix2,1023); iy2 = min(iy2,1023);
        int o = img*NPOS + p;
        scoreAll[o] = sc;
        clsAll[o]   = mi;
        boxAll[o]   = make_float4((float)ix1,(float)iy1,(float)ix2,(float)iy2);
    }
}

// ---- exact K-th-largest, 2-pass radix (bits 31..19, 18..8), BT threads -----
// Result: shPref = 24-bit prefix (<<8) of the K-th value, shK = #kept at that
// prefix (ties resolved exactly by the caller at 24-bit granularity).
// Monotone bins: scores are positive floats < 2.0 -> bits>>19 < 2048.
// Caller must zero histA/histB and __syncthreads() before calling.
__device__ void radix24(const unsigned int* vals, int N, int K,
                        int* histA, int* histB, int* wsum,
                        unsigned int* shPref, int* shK, int tid)
{
    for (int i = tid; i < N; i += BT)
        atomicAdd(&histA[vals[i] >> 19], 1);
    __syncthreads();
    {   // suffix scan over 2048 bins, 2 bins/thread
        int lo = tid*2;
        int ls = histA[lo] + histA[lo+1];
        int lane = tid & 63, wv = tid >> 6;
        int v = ls;
#pragma unroll
        for (int off = 1; off < 64; off <<= 1) {
            int o = __shfl_down(v, off);
            if (lane + off < 64) v += o;
        }
        if (lane == 0) wsum[wv] = v;
        __syncthreads();
        int add = 0;
        for (int q = wv + 1; q < NW; ++q) add += wsum[q];
        int mine = v + add;              // count in bins [lo..2047]
        int above = mine - ls;           // count in bins [lo+2..2047]
        if (above < K && mine >= K) {    // exactly one thread crosses
            if (above + histA[lo+1] >= K) { *shPref = (unsigned)(lo+1) << 19; *shK = K - above; }
            else { *shPref = (unsigned)lo << 19; *shK = K - above - histA[lo+1]; }
        }
        __syncthreads();
    }
    unsigned int pref = *shPref;
    int K2 = *shK;
    for (int i = tid; i < N; i += BT) {
        unsigned int b = vals[i];
        if ((b >> 19) == (pref >> 19)) atomicAdd(&histB[(b >> 8) & 2047], 1);
    }
    __syncthreads();
    {
        int lo = tid*2;
        int ls = histB[lo] + histB[lo+1];
        int lane = tid & 63, wv = tid >> 6;
        int v = ls;
#pragma unroll
        for (int off = 1; off < 64; off <<= 1) {
            int o = __shfl_down(v, off);
            if (lane + off < 64) v += o;
        }
        if (lane == 0) wsum[wv] = v;
        __syncthreads();
        int add = 0;
        for (int q = wv + 1; q < NW; ++q) add += wsum[q];
        int mine = v + add;
        int above = mine - ls;
        if (above < K2 && mine >= K2) {
            if (above + histB[lo+1] >= K2) { *shPref = pref | ((unsigned)(lo+1) << 8); *shK = K2 - above; }
            else { *shPref = pref | ((unsigned)lo << 8); *shK = K2 - above - histB[lo+1]; }
        }
        __syncthreads();
    }
}

// --- Kernel B: per-(img,lvl) exact top-256 -> cKeyG (32 blocks, 1024 thr) ---
// key = (score_bits<<16) | (65535-p): desc key == desc score, ties lower p.
// Top-256/level suffices: top-256 of the union == top-256 of the union of
// per-level top-256 sets (any union-top-256 element is in its level's top-256).
__global__ __launch_bounds__(BT) void k_thresh(const float* scoreAll,
                                               unsigned long long* cKeyG)
{
    __shared__ int histA[2048], histB[2048], wsum[NW];
    __shared__ unsigned int shPref;
    __shared__ int shK, tick, eqn;
    __shared__ int eq[1024];
    int il = blockIdx.x, tid = threadIdx.x;

    if (il >= 24) {                      // blocks 24..31: levels 3+4 copier
        int img = il - 24;
        const unsigned int* gs = (const unsigned int*)scoreAll + (long long)img*NPOS;
        unsigned long long* gk = cKeyG + (long long)img*NCK;
        for (int i = tid; i < 320; i += BT) {
            int p = 21504 + i;
            gk[768 + i] = ((unsigned long long)gs[p] << 16) | (unsigned)(65535 - p);
        }
        return;
    }
    int img = il / 3, lvl = il % 3;
    const int baseA[3] = {0, 16384, 20480};
    const int NlA[3]   = {16384, 4096, 1024};
    int base = baseA[lvl], Nl = NlA[lvl];
    const unsigned int* gs = (const unsigned int*)scoreAll + (long long)img*NPOS + base;
    unsigned long long* gk = cKeyG + (long long)img*NCK + lvl*256;

    for (int i = tid; i < 2048; i += BT) { histA[i] = 0; histB[i] = 0; }
    if (tid == 0) { tick = 0; eqn = 0; }
    __syncthreads();
    radix24(gs, Nl, 256, histA, histB, wsum, &shPref, &shK, tid);
    unsigned int kth = shPref >> 8;      // 24-bit prefix of the K-th value
    int need = shK;                      // #ties to keep (>=1)
    for (int i = tid; i < Nl; i += BT) {
        unsigned int b = gs[i], hb = b >> 8;
        if (hb > kth) {
            int t = atomicAdd(&tick, 1);
            int p = base + i;
            gk[t] = ((unsigned long long)b << 16) | (unsigned)(65535 - p);
        } else if (hb == kth) {
            int t = atomicAdd(&eqn, 1);
            if (t < 1024) eq[t] = i;
        }
    }
    __syncthreads();
    int m = eqn, nG = tick;              // nG == 256-need
    if (m <= 1024) {                     // rank ties: score desc, index asc
        for (int q = tid; q < m; q += BT) {
            int iq = eq[q];
            unsigned int bq = gs[iq];
            int r = 0;
            for (int j = 0; j < m; ++j) {
                int ij = eq[j];
                unsigned int bj = gs[ij];
                r += (bj > bq) || (bj == bq && ij < iq);
            }
            if (r < need) {
                int p = base + iq;
                gk[nG + r] = ((unsigned long long)bq << 16) | (unsigned)(65535 - p);
            }
        }
    } else if (tid == 0) {               // unreachable-in-practice fallback
        unsigned long long last = ~0ULL;
        for (int c = 0; c < need; ++c) {
            unsigned long long best = 0;
            for (int i = 0; i < Nl; ++i) {
                unsigned int b = gs[i];
                if ((b >> 8) == kth) {
                    unsigned long long k = ((unsigned long long)b << 16)
                                         | (unsigned)(65535 - (base + i));
                    if (k < last && k > best) best = k;
                }
            }
            gk[nG + c] = best; last = best;
        }
    }
}

// ------ Kernel C: top-256 select + rank + matrix-NMS (8 blocks, 1024 thr) ---
// Greedy NMS == sequential scan over rank order with a 256-bit suppression
// mask: candidate i accepted iff bit i clear; on accept, OR in row i of the
// precomputed (parallel-built) IoU>thr matrix. Identical decisions to serial
// greedy NMS.
__global__ __launch_bounds__(BT) void k_nms2(const unsigned long long* cKeyG,
                                             const float4* boxAll, const int* clsAll,
                                             float* out)
{
    __shared__ unsigned long long cand[NCK];
    __shared__ unsigned int cbits[NCK];
    __shared__ int histA[2048], histB[2048], wsum[NW];
    __shared__ unsigned int shPref;
    __shared__ int shK, tick, eqn;
    __shared__ int eq[256];
    __shared__ unsigned long long sel[256];
    __shared__ unsigned long long sorted[256];
    __shared__ float4 sBox[256];
    __shared__ float  sCls[256];
    __shared__ __align__(16) unsigned long long sRow[256][4];
    __shared__ int accIdx[100];
    __shared__ int shNaM, shNaT;

    int img = blockIdx.x, tid = threadIdx.x;
    const float4* gBox = boxAll + (long long)img*NPOS;
    const int*    gCls = clsAll + (long long)img*NPOS;
    const unsigned long long* gKey = cKeyG + (long long)img*NCK;

    float* outS = out + img*100;
    float* outC = out + 800 + img*100;
    float* outB = out + 1600 + img*400;

    for (int i = tid; i < NCK; i += BT) {
        unsigned long long k = gKey[i];
        cand[i]  = k;
        cbits[i] = (unsigned int)(k >> 16);
    }
    for (int i = tid; i < 2048; i += BT) { histA[i] = 0; histB[i] = 0; }
    if (tid == 0) { tick = 0; eqn = 0; }
    __syncthreads();

    radix24(cbits, NCK, 256, histA, histB, wsum, &shPref, &shK, tid);
    unsigned int kth2 = shPref >> 8;
    int need2 = shK;
    for (int i = tid; i < NCK; i += BT) {
        unsigned int hb = cbits[i] >> 8;
        if (hb > kth2)       { int t = atomicAdd(&tick, 1); sel[t] = cand[i]; }
        else if (hb == kth2) { int t = atomicAdd(&eqn, 1); if (t < 256) eq[t] = i; }
    }
    __syncthreads();
    int m2 = eqn, nG2 = tick;            // nG2 == 256-need2
    if (m2 <= 256) {                     // keep `need2` LARGEST keys among ties
        for (int q = tid; q < m2; q += BT) {
            unsigned long long kq = cand[eq[q]];
            int r = 0;
            for (int j = 0; j < m2; ++j) r += (cand[eq[j]] > kq);
            if (r < need2) sel[nG2 + r] = kq;
        }
    } else if (tid == 0) {               // unreachable-in-practice fallback
        unsigned long long last = ~0ULL;
        for (int c = 0; c < need2; ++c) {
            unsigned long long best = 0;
            for (int i = 0; i < NCK; ++i) {
                unsigned long long k = cand[i];
                if ((unsigned int)(k >> 24) == kth2 && k < last && k > best) best = k;
            }
            sel[nG2 + c] = best; last = best;
        }
    }
    __syncthreads();

    // rank 256 unique keys by counting (1 key/thread, broadcast LDS reads)
    if (tid < 256) {
        unsigned long long k = sel[tid];
        int r = 0;
        for (int j = 0; j < 256; ++j) r += (sel[j] > k);
        sorted[r] = k;
    }
    __syncthreads();
    if (tid < 256) {
        int p = 65535 - (int)(sorted[tid] & 0xFFFF);
        sBox[tid] = gBox[p];
        sCls[tid] = (float)gCls[p];
    }

    // nValid = # leading candidates with score > MINS (sorted desc, so prefix).
    // __syncthreads_count doubles as the barrier covering sBox/sCls writes.
    float myScore = 0.f;
    if (tid < 256) myScore = __uint_as_float((unsigned int)(sorted[tid] >> 16));
    int nValid = __syncthreads_count(myScore > MINS ? 1 : 0);

    // ---- suppression matrix: thread (row,quarter) builds 64 bits of row ----
    // Float arithmetic order matches serial greedy NMS exactly:
    // den = area(candidate j) + area(accepted i) - inter + 1e-12.
    {
        int row = tid & 255, qq = tid >> 8;
        float4 bi = sBox[row];
        float  ai = (bi.z-bi.x)*(bi.w-bi.y);
        unsigned long long mv = 0;
#pragma unroll 8
        for (int jj = 0; jj < 64; ++jj) {
            int j = qq*64 + jj;
            float4 bj = sBox[j];
            float aj = (bj.z-bj.x)*(bj.w-bj.y);
            float iw = fmaxf(fminf(bj.z,bi.z)-fmaxf(bj.x,bi.x),0.f);
            float ih = fmaxf(fminf(bj.w,bi.w)-fmaxf(bj.y,bi.y),0.f);
            float in_ = iw*ih;
            bool s = (j > row) && (in_/(aj+ai-in_+1e-12f) > 0.6f);
            mv |= ((unsigned long long)s) << jj;
        }
        sRow[row][qq] = mv;
    }
    __syncthreads();

    // ---- serial bitmask walk (thread 0): ~5cy/suppressed, ~130cy/accept ----
    if (tid == 0) {
        int na = 0;
        unsigned long long r0=0, r1=0, r2=0, r3=0;
#define FCOS_WBLK(RW, IB)                                                  \
        {                                                                  \
            int hi = nValid < ((IB)+1)*64 ? nValid : ((IB)+1)*64;          \
            for (int i = (IB)*64; i < hi && na < 100; ++i) {               \
                if ((RW >> (i - (IB)*64)) & 1ull) continue;                \
                accIdx[na++] = i;                                          \
                const ulonglong2* rp = (const ulonglong2*)sRow[i];         \
                ulonglong2 ra = rp[0], rb = rp[1];                         \
                r0 |= ra.x; r1 |= ra.y; r2 |= rb.x; r3 |= rb.y;            \
            }                                                              \
        }
        FCOS_WBLK(r0,0) FCOS_WBLK(r1,1) FCOS_WBLK(r2,2) FCOS_WBLK(r3,3)
#undef FCOS_WBLK
        shNaM = na; shNaT = na;
    }

    // ---- fallback: top-256 exhausted before 100 accepted (never on real data)
    if (tid < 64) {
        int lane = tid;
        int naM = shNaM;                 // lane-0 LDS write, same wave: visible
        if (naM < 100 && nValid == 256) {
            int na = naM;
            float4 aB0 = make_float4(0,0,0,0), aB1 = make_float4(0,0,0,0);
            float  aA0 = 0.f, aA1 = 0.f;
            if (lane < na)      { aB0 = sBox[accIdx[lane]];
                                  aA0 = (aB0.z-aB0.x)*(aB0.w-aB0.y); }
            if (lane + 64 < na) { aB1 = sBox[accIdx[lane+64]];
                                  aA1 = (aB1.z-aB1.x)*(aB1.w-aB1.y); }
            unsigned long long thr = sorted[255];
            for (int j = lane; j < NCK; j += 64)
                if (cand[j] >= thr) cand[j] = 0ULL;    // already consumed
            __threadfence_block();
            while (na < 100) {
                unsigned long long bk = 0; int bidx = -1;
                for (int j = lane; j < NCK; j += 64) {
                    unsigned long long v = cand[j];
                    if (v > bk) { bk = v; bidx = j; }
                }
#pragma unroll
                for (int off = 32; off > 0; off >>= 1) {
                    unsigned long long ov = __shfl_down(bk, off);
                    int oi = __shfl_down(bidx, off);
                    if (ov > bk) { bk = ov; bidx = oi; }
                }
                bk = __shfl(bk, 0); bidx = __shfl(bidx, 0);
                if (bk == 0ULL) break;
                float sc = __uint_as_float((unsigned int)(bk >> 16));
                if (!(sc > MINS)) break;
                int p = 65535 - (int)(bk & 0xFFFF);
                float4 bb2 = gBox[p];
                float ba = (bb2.z-bb2.x)*(bb2.w-bb2.y);
                bool sup = false;
                if (lane < na) {
                    float iw = fmaxf(fminf(bb2.z,aB0.z)-fmaxf(bb2.x,aB0.x),0.f);
                    float ih = fmaxf(fminf(bb2.w,aB0.w)-fmaxf(bb2.y,aB0.y),0.f);
                    float in_ = iw*ih;
                    sup = in_/(ba+aA0-in_+1e-12f) > 0.6f;
                }
                if (lane + 64 < na) {
                    float iw = fmaxf(fminf(bb2.z,aB1.z)-fmaxf(bb2.x,aB1.x),0.f);
                    float ih = fmaxf(fminf(bb2.w,aB1.w)-fmaxf(bb2.y,aB1.y),0.f);
                    float in_ = iw*ih;
                    sup = sup || (in_/(ba+aA1-in_+1e-12f) > 0.6f);
                }
                if (__ballot(sup) == 0ULL) {
                    if (lane == 0) {
                        outS[na] = sc;
                        outC[na] = (float)gCls[p];
                        outB[4*na+0]=bb2.x; outB[4*na+1]=bb2.y;
                        outB[4*na+2]=bb2.z; outB[4*na+3]=bb2.w;
                    }
                    if (lane == (na & 63)) {
                        if (na < 64) { aB0 = bb2; aA0 = ba; }
                        else         { aB1 = bb2; aA1 = ba; }
                    }
                    ++na;
                }
                if (lane == 0) cand[bidx] = 0ULL;
                __threadfence_block();
            }
            if (lane == 0) shNaT = na;
        }
    }
    __syncthreads();

    // ---- parallel epilogue: main accepts from LDS; -1 fill for the rest ----
    {
        int naM = shNaM, naT = shNaT;
        if (tid < 100) {
            if (tid < naM) {
                int r = accIdx[tid];
                unsigned long long k = sorted[r];
                float4 b = sBox[r];
                outS[tid] = __uint_as_float((unsigned int)(k >> 16));
                outC[tid] = sCls[r];
                outB[4*tid+0]=b.x; outB[4*tid+1]=b.y;
                outB[4*tid+2]=b.z; outB[4*tid+3]=b.w;
            } else if (tid >= naT) {     // (naM..naT) written by fallback
                outS[tid] = -1.f; outC[tid] = -1.f;
                outB[4*tid+0]=-1.f; outB[4*tid+1]=-1.f;
                outB[4*tid+2]=-1.f; outB[4*tid+3]=-1.f;
            }
        }
    }
}

extern "C" void kernel_launch(void* const* d_in, const int* in_sizes, int n_in,
                              void* d_out, int out_size, void* d_ws, size_t ws_size,
                              hipStream_t stream) {
    Ptrs P;
    bool interleaved = (in_sizes[1] == 8 * 128 * 128 * 4);
    for (int i = 0; i < 5; ++i) {
        if (interleaved) {
            P.cls[i] = (const float*)d_in[3*i];
            P.reg[i] = (const float*)d_in[3*i + 1];
            P.ctr[i] = (const float*)d_in[3*i + 2];
        } else {
            P.cls[i] = (const float*)d_in[i];
            P.reg[i] = (const float*)d_in[5 + i];
            P.ctr[i] = (const float*)d_in[10 + i];
        }
    }

    char* wbase = (char*)d_ws;
    size_t off = 0;
    auto alloc = [&](size_t bytes) -> void* {
        void* r = wbase + off;
        off += (bytes + 255) & ~(size_t)255;
        return r;
    };
    float*              scoreAll = (float*)alloc((size_t)8 * NPOS * 4);
    int*                clsAll   = (int*)alloc((size_t)8 * NPOS * 4);
    float4*             boxAll   = (float4*)alloc((size_t)8 * NPOS * 16);
    unsigned long long* cKeyG    = (unsigned long long*)alloc((size_t)8 * NCK * 8);

    dim3 gA(341, 8);   // 341*64 = 21824 positions, level boundaries block-aligned
    k_score <<<gA, 256, 0, stream>>>(P, scoreAll, clsAll, boxAll);
    k_thresh<<<32, BT, 0, stream>>>(scoreAll, cKeyG);
    k_nms2  <<<8, BT, 0, stream>>>(cKeyG, boxAll, clsAll, (float*)d_out);
}

// Round 3
// 159.718 us; speedup vs baseline: 1.3944x; 1.0183x over previous
//
#include <hip/hip_runtime.h>

#define NPOS 21824          // 16384+4096+1024+256+64 positions per image
#define MINS 0.05f
#define BT   1024           // threads per block for k_nms (16 waves)
#define NW   (BT/64)

struct Ptrs { const float* cls[5]; const float* reg[5]; const float* ctr[5]; };

__device__ __forceinline__ float sigf(float x){ return 1.0f/(1.0f+expf(-x)); }

// key = (score_bits<<16) | (65535-p): desc key == desc score, ties lower p.
// Matches reference ordering (concatenation order = level-major position p;
// argmax picks first max; jax top_k keeps lower index on ties).
__device__ __forceinline__ unsigned long long mkkey(unsigned int b, int p){
    return ((unsigned long long)b << 16) | (unsigned)(65535 - p);
}

// ---------------- Kernel A: score / class / box, 4 lanes per position -------
__global__ __launch_bounds__(256) void k_score(Ptrs P, float* scoreAll, int* clsAll,
                                               float4* boxAll)
{
    int img  = blockIdx.y;
    int blk  = blockIdx.x;           // [0,341)
    int tid  = threadIdx.x;
    int posb = tid >> 2;             // position within block [0,64)
    int l    = tid & 3;              // lane within 4-lane group
    int p    = blk*64 + posb;
    int lvl, base, lw, stride;
    if (blk < 256)      { lvl=0; base=0;     lw=7; stride=8;   }
    else if (blk < 320) { lvl=1; base=16384; lw=6; stride=16;  }
    else if (blk < 336) { lvl=2; base=20480; lw=5; stride=32;  }
    else if (blk < 340) { lvl=3; base=21504; lw=4; stride=64;  }
    else                { lvl=4; base=21760; lw=3; stride=128; }
    int pl = p - base;
    int h = pl >> lw, w = pl & ((1<<lw)-1);
    long long lidx = (long long)img*(1<<(2*lw)) + pl;

    const float4* c4 = (const float4*)(P.cls[lvl] + lidx*80);
    float mx = -3.4e38f; int mi = 0;
#pragma unroll
    for (int j = 0; j < 5; ++j) {
        int k = j*4 + l;
        float4 v = c4[k];
        int cb = k*4;
        if (v.x > mx){mx=v.x; mi=cb;}
        if (v.y > mx){mx=v.y; mi=cb+1;}
        if (v.z > mx){mx=v.z; mi=cb+2;}
        if (v.w > mx){mx=v.w; mi=cb+3;}
    }
#pragma unroll
    for (int d = 1; d < 4; d <<= 1) {
        float omx = __shfl_xor(mx, d);
        int   omi = __shfl_xor(mi, d);
        if (omx > mx || (omx == mx && omi < mi)) { mx = omx; mi = omi; }
    }
    if (l == 0) {
        float ct = P.ctr[lvl][lidx];
        float sc = sqrtf(sigf(mx)*sigf(ct));   // sigmoid(max)==max(sigmoid)
        float4 rg = ((const float4*)P.reg[lvl])[lidx];
        float x = (w + 0.5f)*(float)stride;
        float y = (h + 0.5f)*(float)stride;
        int ix1 = (int)(x - expf(rg.x));
        int iy1 = (int)(y - expf(rg.y));
        int ix2 = (int)(x + expf(rg.z));
        int iy2 = (int)(y + expf(rg.w));
        ix1 = max(ix1,0); iy1 = max(iy1,0);
        ix2 = min(ix2,1023); iy2 = min(iy2,1023);
        int o = img*NPOS + p;
        scoreAll[o] = sc;
        clsAll[o]   = mi;
        boxAll[o]   = make_float4((float)ix1,(float)iy1,(float)ix2,(float)iy2);
    }
}

// ---- exact K-th-largest, 2-pass radix (bits 31..19, 18..8), BT threads -----
// Result: shPref = 24-bit prefix (<<8) of the K-th value, shK = #kept at that
// prefix (ties resolved exactly by the caller at 24-bit granularity).
// Monotone bins: scores are positive floats < 1.0 -> bits>>19 < 2048.
// Caller must zero histA/histB and __syncthreads() before calling.
__device__ void radix24(const unsigned int* vals, int N, int K,
                        int* histA, int* histB, int* wsum,
                        unsigned int* shPref, int* shK, int tid)
{
    for (int i = tid; i < N; i += BT)
        atomicAdd(&histA[vals[i] >> 19], 1);
    __syncthreads();
    {   // suffix scan over 2048 bins, 2 bins/thread
        int lo = tid*2;
        int ls = histA[lo] + histA[lo+1];
        int lane = tid & 63, wv = tid >> 6;
        int v = ls;
#pragma unroll
        for (int off = 1; off < 64; off <<= 1) {
            int o = __shfl_down(v, off);
            if (lane + off < 64) v += o;
        }
        if (lane == 0) wsum[wv] = v;
        __syncthreads();
        int add = 0;
        for (int q = wv + 1; q < NW; ++q) add += wsum[q];
        int mine = v + add;              // count in bins [lo..2047]
        int above = mine - ls;           // count in bins [lo+2..2047]
        if (above < K && mine >= K) {    // exactly one thread crosses
            if (above + histA[lo+1] >= K) { *shPref = (unsigned)(lo+1) << 19; *shK = K - above; }
            else { *shPref = (unsigned)lo << 19; *shK = K - above - histA[lo+1]; }
        }
        __syncthreads();
    }
    unsigned int pref = *shPref;
    int K2 = *shK;
    for (int i = tid; i < N; i += BT) {
        unsigned int b = vals[i];
        if ((b >> 19) == (pref >> 19)) atomicAdd(&histB[(b >> 8) & 2047], 1);
    }
    __syncthreads();
    {
        int lo = tid*2;
        int ls = histB[lo] + histB[lo+1];
        int lane = tid & 63, wv = tid >> 6;
        int v = ls;
#pragma unroll
        for (int off = 1; off < 64; off <<= 1) {
            int o = __shfl_down(v, off);
            if (lane + off < 64) v += o;
        }
        if (lane == 0) wsum[wv] = v;
        __syncthreads();
        int add = 0;
        for (int q = wv + 1; q < NW; ++q) add += wsum[q];
        int mine = v + add;
        int above = mine - ls;
        if (above < K2 && mine >= K2) {
            if (above + histB[lo+1] >= K2) { *shPref = pref | ((unsigned)(lo+1) << 8); *shK = K2 - above; }
            else { *shPref = pref | ((unsigned)lo << 8); *shK = K2 - above - histB[lo+1]; }
        }
        __syncthreads();
    }
}

// ------ Kernel B: global top-256 + rank + matrix-NMS (8 blocks, 1024 thr) ---
// Global top-256 over all positions == top-256 of the reference's union pool:
// any global-top-256 element has <256 same-level predecessors under
// (score desc, pos asc), so it's inside its level's top-1000. No per-level
// pre-selection kernel needed.
// Greedy NMS == sequential scan over rank order with a 256-bit suppression
// mask: candidate i accepted iff bit i clear; on accept, OR in row i of the
// precomputed (parallel-built) IoU>thr matrix. Identical decisions to serial
// greedy NMS.
__global__ __launch_bounds__(BT) void k_nms(const float* scoreAll,
                                            const float4* boxAll, const int* clsAll,
                                            float* out)
{
    __shared__ int histA[2048], histB[2048], wsum[NW];
    __shared__ unsigned int shPref;
    __shared__ int shK, tick, eqn;
    __shared__ unsigned long long eqKey[1024];
    __shared__ unsigned long long sel[256];
    __shared__ unsigned long long sorted[256];
    __shared__ float4 sBox[256];
    __shared__ float  sCls[256];
    __shared__ __align__(16) unsigned long long sRow[256][4];
    __shared__ int accIdx[100];
    __shared__ float4 accBox[100];
    __shared__ int shNaM, shNa;
    __shared__ unsigned long long shLast;

    int img = blockIdx.x, tid = threadIdx.x;
    const unsigned int* gs = (const unsigned int*)scoreAll + (long long)img*NPOS;
    const float4* gBox = boxAll + (long long)img*NPOS;
    const int*    gCls = clsAll + (long long)img*NPOS;

    float* outS = out + img*100;
    float* outC = out + 800 + img*100;
    float* outB = out + 1600 + img*400;

    for (int i = tid; i < 2048; i += BT) { histA[i] = 0; histB[i] = 0; }
    if (tid == 0) { tick = 0; eqn = 0; }
    __syncthreads();

    radix24(gs, NPOS, 256, histA, histB, wsum, &shPref, &shK, tid);
    unsigned int kth = shPref >> 8;      // 24-bit prefix of the 256th value
    int need = shK;                      // #ties to keep (>=1)
    for (int i = tid; i < NPOS; i += BT) {
        unsigned int b = gs[i], hb = b >> 8;
        if (hb > kth)       { int t = atomicAdd(&tick, 1); sel[t] = mkkey(b, i); }
        else if (hb == kth) { int t = atomicAdd(&eqn, 1); if (t < 1024) eqKey[t] = mkkey(b, i); }
    }
    __syncthreads();
    int m = eqn, nG = tick;              // nG == 256-need
    if (m <= 1024) {                     // keep `need` LARGEST keys among ties
        for (int q = tid; q < m; q += BT) {
            unsigned long long kq = eqKey[q];
            int r = 0;
            for (int j = 0; j < m; ++j) r += (eqKey[j] > kq);
            if (r < need) sel[nG + r] = kq;
        }
    } else if (tid == 0) {               // unreachable-in-practice fallback
        unsigned long long last = ~0ULL;
        for (int c = 0; c < need; ++c) {
            unsigned long long best = 0;
            for (int i = 0; i < NPOS; ++i) {
                unsigned int b = gs[i];
                if ((b >> 8) == kth) {
                    unsigned long long k2 = mkkey(b, i);
                    if (k2 < last && k2 > best) best = k2;
                }
            }
            sel[nG + c] = best; last = best;
        }
    }
    __syncthreads();

    // rank 256 unique keys by counting (1 key/thread, broadcast LDS reads)
    if (tid < 256) {
        unsigned long long k = sel[tid];
        int r = 0;
        for (int j = 0; j < 256; ++j) r += (sel[j] > k);
        sorted[r] = k;
    }
    __syncthreads();
    if (tid < 256) {
        int p = 65535 - (int)(sorted[tid] & 0xFFFF);
        sBox[tid] = gBox[p];
        sCls[tid] = (float)gCls[p];
    }

    // nValid = # leading candidates with score > MINS (sorted desc, so prefix).
    // __syncthreads_count doubles as the barrier covering sBox/sCls writes.
    float myScore = 0.f;
    if (tid < 256) myScore = __uint_as_float((unsigned int)(sorted[tid] >> 16));
    int nValid = __syncthreads_count(myScore > MINS ? 1 : 0);

    // ---- suppression matrix: thread (row,quarter) builds 64 bits of row ----
    // Float arithmetic order matches serial greedy NMS exactly:
    // den = area(candidate j) + area(accepted i) - inter + 1e-12.
    {
        int row = tid & 255, qq = tid >> 8;
        float4 bi = sBox[row];
        float  ai = (bi.z-bi.x)*(bi.w-bi.y);
        unsigned long long mv = 0;
#pragma unroll 8
        for (int jj = 0; jj < 64; ++jj) {
            int j = qq*64 + jj;
            float4 bj = sBox[j];
            float aj = (bj.z-bj.x)*(bj.w-bj.y);
            float iw = fmaxf(fminf(bj.z,bi.z)-fmaxf(bj.x,bi.x),0.f);
            float ih = fmaxf(fminf(bj.w,bi.w)-fmaxf(bj.y,bi.y),0.f);
            float in_ = iw*ih;
            bool s = (j > row) && (in_/(aj+ai-in_+1e-12f) > 0.6f);
            mv |= ((unsigned long long)s) << jj;
        }
        sRow[row][qq] = mv;
    }
    __syncthreads();

    // ---- serial bitmask walk (thread 0): ~5cy/suppressed, ~130cy/accept ----
    if (tid == 0) {
        int na = 0;
        unsigned long long r0=0, r1=0, r2=0, r3=0;
#define FCOS_WBLK(RW, IB)                                                  \
        {                                                                  \
            int hi = nValid < ((IB)+1)*64 ? nValid : ((IB)+1)*64;          \
            for (int i = (IB)*64; i < hi && na < 100; ++i) {               \
                if ((RW >> (i - (IB)*64)) & 1ull) continue;                \
                accIdx[na++] = i;                                          \
                const ulonglong2* rp = (const ulonglong2*)sRow[i];         \
                ulonglong2 ra = rp[0], rb = rp[1];                         \
                r0 |= ra.x; r1 |= ra.y; r2 |= rb.x; r3 |= rb.y;            \
            }                                                              \
        }
        FCOS_WBLK(r0,0) FCOS_WBLK(r1,1) FCOS_WBLK(r2,2) FCOS_WBLK(r3,3)
#undef FCOS_WBLK
        shNaM = na; shNa = na;
    }
    __syncthreads();

    // ---- fallback: top-256 exhausted before 100 accepted (never on real ----
    // data; guarded by nValid==256 since keys below rank 256 have score <=
    // sorted[255]'s). Full-block scan over all positions per step.
    int naM = shNaM;
    if (naM < 100 && nValid == 256) {
        if (tid < naM) accBox[tid] = sBox[accIdx[tid]];
        if (tid == 0) shLast = sorted[255];
        __syncthreads();
        while (true) {
            if (shNa >= 100) break;
            unsigned long long last = shLast;
            unsigned long long bk = 0;
            for (int i = tid; i < NPOS; i += BT) {
                unsigned long long k2 = mkkey(gs[i], i);
                if (k2 < last && k2 > bk) bk = k2;
            }
#pragma unroll
            for (int off = 32; off > 0; off >>= 1) {
                unsigned long long o = __shfl_down(bk, off);
                if (o > bk) bk = o;
            }
            int lane = tid & 63, wv = tid >> 6;
            if (lane == 0) eqKey[wv] = bk;
            __syncthreads();
            if (tid == 0) {
                unsigned long long best = 0;
                for (int q = 0; q < NW; ++q) if (eqKey[q] > best) best = eqKey[q];
                shLast = best;
            }
            __syncthreads();
            unsigned long long ck = shLast;
            if (ck == 0ULL) break;
            float sc = __uint_as_float((unsigned int)(ck >> 16));
            if (!(sc > MINS)) break;
            int p = 65535 - (int)(ck & 0xFFFF);
            float4 bb = gBox[p];
            float ba = (bb.z-bb.x)*(bb.w-bb.y);
            int na = shNa;
            bool mySup = false;
            if (tid < na) {
                float4 ab = accBox[tid];
                float aa = (ab.z-ab.x)*(ab.w-ab.y);
                float iw = fmaxf(fminf(bb.z,ab.z)-fmaxf(bb.x,ab.x),0.f);
                float ih = fmaxf(fminf(bb.w,ab.w)-fmaxf(bb.y,ab.y),0.f);
                float in_ = iw*ih;
                mySup = in_/(ba+aa-in_+1e-12f) > 0.6f;
            }
            int supCnt = __syncthreads_count(mySup);
            if (supCnt == 0) {
                if (tid == 0) {
                    int na2 = shNa;
                    outS[na2] = sc;
                    outC[na2] = (float)gCls[p];
                    outB[4*na2+0]=bb.x; outB[4*na2+1]=bb.y;
                    outB[4*na2+2]=bb.z; outB[4*na2+3]=bb.w;
                    accBox[na2] = bb;
                    shNa = na2 + 1;
                }
            }
            __syncthreads();
        }
    }
    __syncthreads();

    // ---- parallel epilogue: main accepts from LDS; -1 fill for the rest ----
    {
        int naM2 = shNaM, naT = shNa;
        if (tid < 100) {
            if (tid < naM2) {
                int r = accIdx[tid];
                unsigned long long k = sorted[r];
                float4 b = sBox[r];
                outS[tid] = __uint_as_float((unsigned int)(k >> 16));
                outC[tid] = sCls[r];
                outB[4*tid+0]=b.x; outB[4*tid+1]=b.y;
                outB[4*tid+2]=b.z; outB[4*tid+3]=b.w;
            } else if (tid >= naT) {     // (naM..naT) written by fallback
                outS[tid] = -1.f; outC[tid] = -1.f;
                outB[4*tid+0]=-1.f; outB[4*tid+1]=-1.f;
                outB[4*tid+2]=-1.f; outB[4*tid+3]=-1.f;
            }
        }
    }
}

extern "C" void kernel_launch(void* const* d_in, const int* in_sizes, int n_in,
                              void* d_out, int out_size, void* d_ws, size_t ws_size,
                              hipStream_t stream) {
    Ptrs P;
    bool interleaved = (in_sizes[1] == 8 * 128 * 128 * 4);
    for (int i = 0; i < 5; ++i) {
        if (interleaved) {
            P.cls[i] = (const float*)d_in[3*i];
            P.reg[i] = (const float*)d_in[3*i + 1];
            P.ctr[i] = (const float*)d_in[3*i + 2];
        } else {
            P.cls[i] = (const float*)d_in[i];
            P.reg[i] = (const float*)d_in[5 + i];
            P.ctr[i] = (const float*)d_in[10 + i];
        }
    }

    char* wbase = (char*)d_ws;
    size_t off = 0;
    auto alloc = [&](size_t bytes) -> void* {
        void* r = wbase + off;
        off += (bytes + 255) & ~(size_t)255;
        return r;
    };
    float*  scoreAll = (float*)alloc((size_t)8 * NPOS * 4);
    int*    clsAll   = (int*)alloc((size_t)8 * NPOS * 4);
    float4* boxAll   = (float4*)alloc((size_t)8 * NPOS * 16);

    dim3 gA(341, 8);   // 341*64 = 21824 positions, level boundaries block-aligned
    k_score <<<gA, 256, 0, stream>>>(P, scoreAll, clsAll, boxAll);
    k_nms   <<<8, BT, 0, stream>>>(scoreAll, boxAll, clsAll, (float*)d_out);
}